// Round 8
// baseline (156.153 us; speedup 1.0000x reference)
//
#include <hip/hip_runtime.h>

namespace {
constexpr int Wd = 160, Hd = 192, Dd = 160, Bd = 2;
constexpr int HW = Hd * Wd;
constexpr int DCHUNK = 10;
constexpr int NCHUNK = Dd / DCHUNK;   // 16
constexpr int WGROUPS = 5;            // 32-float w-groups
constexpr int HSUPER = 6;             // supertiles of 32 rows (4 waves x 8)
constexpr float EPS = 1e-8f;
}

__device__ __forceinline__ float dpp_up1(float v) {   // lane i <- lane i-1
  return __int_as_float(__builtin_amdgcn_update_dpp(
      0, __float_as_int(v), 0x138, 0xF, 0xF, true));  // wave_shr:1
}
__device__ __forceinline__ float dpp_dn1(float v) {   // lane i <- lane i+1
  return __int_as_float(__builtin_amdgcn_update_dpp(
      0, __float_as_int(v), 0x130, 0xF, 0xF, true));  // wave_shl:1
}

__global__ __launch_bounds__(256, 4) void sobel_loss_kernel(
    const float* __restrict__ pred, const float* __restrict__ targ,
    float* __restrict__ out) {
  const int tid = threadIdx.x;
  const int lane = tid & 63;
  const int wv = tid >> 6;
  const int r = lane >> 3, s = lane & 7;     // 8 rows x 8 strips per wave
  const int wg = blockIdx.x % WGROUPS;
  const int hs = blockIdx.x / WGROUPS;
  const int hr = (hs * 4 + wv) * 8 + r;      // output row 0..191
  const int gb = wg * 32;                    // w-group base
  const int d0 = blockIdx.y * DCHUNK;
  const uint32_t vol = (uint32_t)blockIdx.z * (uint32_t)(Dd * HW);

  // loop-invariant row offsets + validity (h zero-pad via never-written regs)
  uint32_t roff[3];
  bool rv[3];
#pragma unroll
  for (int k = 0; k < 3; ++k) {
    const int hh = hr - 1 + k;
    rv[k] = (unsigned)hh < (unsigned)Hd;
    roff[k] = vol + (uint32_t)((rv[k] ? hh : 0) * Wd + gb + s * 4);
  }
  const bool eL = (s == 0), eR = (s == 7);
  const bool ev = (eL && gb > 0) || (eR && gb + 32 < Wd);
  const int hd = eL ? -1 : 4;                // halo scalar: roff + hd

  float4 y[2][3];                            // 3 rows x 2 tensors, current slice
  float hv[2][3];                            // edge halo scalars (0 if invalid)
#pragma unroll
  for (int t = 0; t < 2; ++t)
#pragma unroll
    for (int k = 0; k < 3; ++k) { y[t][k] = float4{0.f, 0.f, 0.f, 0.f}; hv[t][k] = 0.f; }

  auto LOADT = [&](const float* __restrict__ bp, int ti, int d) {
    if ((unsigned)d < (unsigned)Dd) {
      const uint32_t doff = (uint32_t)d * (uint32_t)HW;
#pragma unroll
      for (int k = 0; k < 3; ++k) {
        if (rv[k]) {
          y[ti][k] = *reinterpret_cast<const float4*>(bp + doff + roff[k]);
          if (ev) hv[ti][k] = bp[doff + roff[k] + hd];
        }
      }
    } else {
#pragma unroll
      for (int k = 0; k < 3; ++k) { y[ti][k] = float4{0.f, 0.f, 0.f, 0.f}; hv[ti][k] = 0.f; }
    }
  };

  // fused w-conv + h-combine for one tensor's current slice
  auto ABCc = [&](int ti, float (&A)[4], float (&B)[4], float (&C)[4]) {
    float sw0[4];
    {  // row r-1
      const float4 yy = y[ti][0];
      float xl = dpp_up1(yy.w); xl = eL ? hv[ti][0] : xl;
      float xr = dpp_dn1(yy.x); xr = eR ? hv[ti][0] : xr;
      const float x[6] = {xl, yy.x, yy.y, yy.z, yy.w, xr};
#pragma unroll
      for (int j = 0; j < 4; ++j) {
        sw0[j] = fmaf(2.f, x[j + 1], x[j] + x[j + 2]);
        A[j] = sw0[j];
        B[j] = x[j + 2] - x[j];
      }
    }
    {  // row r
      const float4 yy = y[ti][1];
      float xl = dpp_up1(yy.w); xl = eL ? hv[ti][1] : xl;
      float xr = dpp_dn1(yy.x); xr = eR ? hv[ti][1] : xr;
      const float x[6] = {xl, yy.x, yy.y, yy.z, yy.w, xr};
#pragma unroll
      for (int j = 0; j < 4; ++j) {
        const float sw = fmaf(2.f, x[j + 1], x[j] + x[j + 2]);
        const float dw = x[j + 2] - x[j];
        A[j] = fmaf(2.f, sw, A[j]);
        B[j] = fmaf(2.f, dw, B[j]);
      }
    }
    {  // row r+1
      const float4 yy = y[ti][2];
      float xl = dpp_up1(yy.w); xl = eL ? hv[ti][2] : xl;
      float xr = dpp_dn1(yy.x); xr = eR ? hv[ti][2] : xr;
      const float x[6] = {xl, yy.x, yy.y, yy.z, yy.w, xr};
#pragma unroll
      for (int j = 0; j < 4; ++j) {
        const float sw = fmaf(2.f, x[j + 1], x[j] + x[j + 2]);
        const float dw = x[j + 2] - x[j];
        A[j] += sw;
        B[j] += dw;
        C[j] = sw - sw0[j];
      }
    }
  };

  // rolling d-state: 6 regs per (tensor, j)
  float gxp[2][4] = {}, Bp[2][4] = {}, gyp[2][4] = {}, Cp[2][4] = {};
  float Ap[2][4] = {}, App[2][4] = {};
  float mag[2][4];
  float acc = 0.f;

  auto ABSORB = [&](int ti, float (&A)[4], float (&B)[4], float (&C)[4], bool emit) {
#pragma unroll
    for (int j = 0; j < 4; ++j) {
      if (emit) {
        const float gx = gxp[ti][j] + B[j];
        const float gy = gyp[ti][j] + C[j];
        const float gz = A[j] - App[ti][j];
        mag[ti][j] = sqrtf(fmaf(gx, gx, fmaf(gy, gy, fmaf(gz, gz, EPS))));
      }
      gxp[ti][j] = fmaf(2.f, B[j], Bp[ti][j]); Bp[ti][j] = B[j];
      gyp[ti][j] = fmaf(2.f, C[j], Cp[ti][j]); Cp[ti][j] = C[j];
      App[ti][j] = Ap[ti][j];  Ap[ti][j] = A[j];
    }
  };

  float A0[4], B0[4], C0[4], A1[4], B1[4], C1[4];

  // ---- prologue: absorb slices d0-1 and d0 (no emit) ----
  LOADT(pred, 0, d0 - 1); LOADT(targ, 1, d0 - 1);
  ABCc(0, A0, B0, C0); LOADT(pred, 0, d0);     ABSORB(0, A0, B0, C0, false);
  ABCc(1, A1, B1, C1); LOADT(targ, 1, d0);     ABSORB(1, A1, B1, C1, false);
  ABCc(0, A0, B0, C0); LOADT(pred, 0, d0 + 1); ABSORB(0, A0, B0, C0, false);
  ABCc(1, A1, B1, C1); LOADT(targ, 1, d0 + 1); ABSORB(1, A1, B1, C1, false);

  // ---- main: absorb slice d0+k -> emit slice d0+k-1; loads for k+1 issued
  //      mid-iteration (consumed next iteration = full covering distance) ----
#pragma unroll 2
  for (int k = 1; k <= DCHUNK; ++k) {
    ABCc(0, A0, B0, C0);
    if (k < DCHUNK) LOADT(pred, 0, d0 + k + 1);
    ABSORB(0, A0, B0, C0, true);
    ABCc(1, A1, B1, C1);
    if (k < DCHUNK) LOADT(targ, 1, d0 + k + 1);
    ABSORB(1, A1, B1, C1, true);
#pragma unroll
    for (int j = 0; j < 4; ++j) acc += fabsf(mag[0][j] - mag[1][j]);
  }

  // ---- reduction: wave shfl -> LDS(4 floats) -> one atomic per block ----
  float sred = acc;
#pragma unroll
  for (int off = 32; off > 0; off >>= 1) sred += __shfl_down(sred, off, 64);
  __shared__ float wsum[4];
  if (lane == 0) wsum[wv] = sred;
  __syncthreads();
  if (tid == 0) {
    atomicAdd(out, (wsum[0] + wsum[1] + wsum[2] + wsum[3]) *
                       (1.0f / (float)((size_t)Bd * Dd * Hd * Wd)));
  }
}

extern "C" void kernel_launch(void* const* d_in, const int* in_sizes, int n_in,
                              void* d_out, int out_size, void* d_ws, size_t ws_size,
                              hipStream_t stream) {
  const float* pred = (const float*)d_in[0];
  const float* targ = (const float*)d_in[1];
  float* out = (float*)d_out;
  (void)in_sizes; (void)n_in; (void)out_size; (void)d_ws; (void)ws_size;

  hipMemsetAsync(out, 0, sizeof(float), stream);
  dim3 grid(WGROUPS * HSUPER, NCHUNK, Bd);
  sobel_loss_kernel<<<grid, 256, 0, stream>>>(pred, targ, out);
}

// Round 9
// 139.563 us; speedup vs baseline: 1.1189x; 1.1189x over previous
//
#include <hip/hip_runtime.h>

namespace {
constexpr int Wd = 160, Hd = 192, Dd = 160, Bd = 2;
constexpr int HW = Hd * Wd;
constexpr int DCHUNK = 10;
constexpr int NCHUNK = Dd / DCHUNK;   // 16
constexpr int WGROUPS = 5;            // 32-float w-groups
constexpr int HSUPER = 6;             // supertiles of 32 rows (4 waves x 8)
constexpr float EPS = 1e-8f;
}

__device__ __forceinline__ float dpp_up1(float v) {   // lane i <- lane i-1
  return __int_as_float(__builtin_amdgcn_update_dpp(
      0, __float_as_int(v), 0x138, 0xF, 0xF, true));  // wave_shr:1
}
__device__ __forceinline__ float dpp_dn1(float v) {   // lane i <- lane i+1
  return __int_as_float(__builtin_amdgcn_update_dpp(
      0, __float_as_int(v), 0x130, 0xF, 0xF, true));  // wave_shl:1
}

// ---- per-tensor state, all distinctly named (no runtime-indexed arrays) ----
#define DECL_STATE(S)                                                   \
  float4 y0##S, y1##S, y2##S;                                           \
  float h0##S = 0.f, h1##S = 0.f, h2##S = 0.f;                          \
  float gxp##S[4] = {}, Bp##S[4] = {}, gyp##S[4] = {}, Cp##S[4] = {},   \
        Ap##S[4] = {}, App##S[4] = {};                                  \
  float mag##S[4];

#define LOADT(S, bp, d)                                                       \
  do {                                                                        \
    const bool dok_ = (unsigned)(d) < (unsigned)Dd;                           \
    const uint32_t doff_ = (uint32_t)(dok_ ? (d) : 0) * (uint32_t)HW;         \
    const float4 z4_ = float4{0.f, 0.f, 0.f, 0.f};                            \
    y0##S = (dok_ && rv0) ? *(const float4*)((bp) + doff_ + roff0) : z4_;     \
    y1##S = (dok_ && rv1) ? *(const float4*)((bp) + doff_ + roff1) : z4_;     \
    y2##S = (dok_ && rv2) ? *(const float4*)((bp) + doff_ + roff2) : z4_;     \
    h0##S = (dok_ && ev && rv0) ? (bp)[doff_ + roff0 + hd] : 0.f;             \
    h1##S = (dok_ && ev && rv1) ? (bp)[doff_ + roff1 + hd] : 0.f;             \
    h2##S = (dok_ && ev && rv2) ? (bp)[doff_ + roff2 + hd] : 0.f;             \
  } while (0)

// one row of fused w-conv; OP: =, += with weight
#define ROW(S, YY, HH, STMT)                                                  \
  do {                                                                        \
    const float4 yy_ = YY;                                                    \
    float xl_ = dpp_up1(yy_.w); if (eL) xl_ = HH;                             \
    float xr_ = dpp_dn1(yy_.x); if (eR) xr_ = HH;                             \
    const float x0 = xl_, x1 = yy_.x, x2 = yy_.y, x3 = yy_.z, x4 = yy_.w,     \
                x5 = xr_;                                                     \
    STMT                                                                      \
  } while (0)

#define ABCC(S, A, B, C)                                                      \
  do {                                                                        \
    float s0_[4];                                                             \
    ROW(S, y0##S, h0##S, {                                                    \
      s0_[0] = fmaf(2.f, x1, x0 + x2); s0_[1] = fmaf(2.f, x2, x1 + x3);       \
      s0_[2] = fmaf(2.f, x3, x2 + x4); s0_[3] = fmaf(2.f, x4, x3 + x5);       \
      A[0] = s0_[0]; A[1] = s0_[1]; A[2] = s0_[2]; A[3] = s0_[3];             \
      B[0] = x2 - x0; B[1] = x3 - x1; B[2] = x4 - x2; B[3] = x5 - x3;         \
    });                                                                       \
    ROW(S, y1##S, h1##S, {                                                    \
      A[0] = fmaf(2.f, fmaf(2.f, x1, x0 + x2), A[0]);                         \
      A[1] = fmaf(2.f, fmaf(2.f, x2, x1 + x3), A[1]);                         \
      A[2] = fmaf(2.f, fmaf(2.f, x3, x2 + x4), A[2]);                         \
      A[3] = fmaf(2.f, fmaf(2.f, x4, x3 + x5), A[3]);                         \
      B[0] = fmaf(2.f, x2 - x0, B[0]); B[1] = fmaf(2.f, x3 - x1, B[1]);       \
      B[2] = fmaf(2.f, x4 - x2, B[2]); B[3] = fmaf(2.f, x5 - x3, B[3]);       \
    });                                                                       \
    ROW(S, y2##S, h2##S, {                                                    \
      float sw_;                                                              \
      sw_ = fmaf(2.f, x1, x0 + x2); A[0] += sw_; C[0] = sw_ - s0_[0];         \
      sw_ = fmaf(2.f, x2, x1 + x3); A[1] += sw_; C[1] = sw_ - s0_[1];         \
      sw_ = fmaf(2.f, x3, x2 + x4); A[2] += sw_; C[2] = sw_ - s0_[2];         \
      sw_ = fmaf(2.f, x4, x3 + x5); A[3] += sw_; C[3] = sw_ - s0_[3];         \
      B[0] += x2 - x0; B[1] += x3 - x1; B[2] += x4 - x2; B[3] += x5 - x3;     \
    });                                                                       \
  } while (0)

#define ABSORB(S, A, B, C, EMIT)                                              \
  _Pragma("unroll") for (int j = 0; j < 4; ++j) {                             \
    if (EMIT) {                                                               \
      const float gx_ = gxp##S[j] + B[j];                                     \
      const float gy_ = gyp##S[j] + C[j];                                     \
      const float gz_ = A[j] - App##S[j];                                     \
      mag##S[j] = sqrtf(fmaf(gx_, gx_, fmaf(gy_, gy_, fmaf(gz_, gz_, EPS)))); \
    }                                                                         \
    gxp##S[j] = fmaf(2.f, B[j], Bp##S[j]); Bp##S[j] = B[j];                   \
    gyp##S[j] = fmaf(2.f, C[j], Cp##S[j]); Cp##S[j] = C[j];                   \
    App##S[j] = Ap##S[j]; Ap##S[j] = A[j];                                    \
  }

__global__ __launch_bounds__(256, 3) void sobel_loss_kernel(
    const float* __restrict__ pred, const float* __restrict__ targ,
    float* __restrict__ out) {
  const int tid = threadIdx.x;
  const int lane = tid & 63;
  const int wv = tid >> 6;
  const int r = lane >> 3, s = lane & 7;     // 8 rows x 8 strips per wave
  const int wg = blockIdx.x % WGROUPS;
  const int hs = blockIdx.x / WGROUPS;
  const int hr = (hs * 4 + wv) * 8 + r;      // output row 0..191
  const int gb = wg * 32;                    // w-group base
  const int d0 = blockIdx.y * DCHUNK;
  const uint32_t vol = (uint32_t)blockIdx.z * (uint32_t)(Dd * HW);

  const bool rv0 = (unsigned)(hr - 1) < (unsigned)Hd;
  const bool rv1 = true;                     // hr in [0,191] always valid
  const bool rv2 = (unsigned)(hr + 1) < (unsigned)Hd;
  const uint32_t roff0 = vol + (uint32_t)((rv0 ? hr - 1 : 0) * Wd + gb + s * 4);
  const uint32_t roff1 = vol + (uint32_t)(hr * Wd + gb + s * 4);
  const uint32_t roff2 = vol + (uint32_t)((rv2 ? hr + 1 : 0) * Wd + gb + s * 4);
  const bool eL = (s == 0), eR = (s == 7);
  const bool ev = (eL && gb > 0) || (eR && gb + 32 < Wd);
  const int hd = eL ? -1 : 4;                // halo scalar offset

  DECL_STATE(P)
  DECL_STATE(T)
  float A0[4], B0[4], C0[4], A1[4], B1[4], C1[4];
  float acc = 0.f;

  // ---- prologue: absorb slices d0-1 and d0 (no emit); leaves y = slice d0+1
  LOADT(P, pred, d0 - 1);
  LOADT(T, targ, d0 - 1);
  ABCC(P, A0, B0, C0); LOADT(P, pred, d0);     ABSORB(P, A0, B0, C0, false)
  ABCC(T, A1, B1, C1); LOADT(T, targ, d0);     ABSORB(T, A1, B1, C1, false)
  ABCC(P, A0, B0, C0); LOADT(P, pred, d0 + 1); ABSORB(P, A0, B0, C0, false)
  ABCC(T, A1, B1, C1); LOADT(T, targ, d0 + 1); ABSORB(T, A1, B1, C1, false)

  // ---- main: absorb slice d0+k -> emit slice d0+k-1; next-slice loads issued
  //      mid-iteration, consumed next iteration (full covering distance) ----
#pragma unroll 2
  for (int k = 1; k <= DCHUNK; ++k) {
    ABCC(P, A0, B0, C0);
    if (k < DCHUNK) LOADT(P, pred, d0 + k + 1);
    ABSORB(P, A0, B0, C0, true)
    ABCC(T, A1, B1, C1);
    if (k < DCHUNK) LOADT(T, targ, d0 + k + 1);
    ABSORB(T, A1, B1, C1, true)
    acc += fabsf(magP[0] - magT[0]) + fabsf(magP[1] - magT[1]) +
           fabsf(magP[2] - magT[2]) + fabsf(magP[3] - magT[3]);
  }

  // ---- reduction: wave shfl -> LDS(4 floats) -> one atomic per block ----
  float sred = acc;
#pragma unroll
  for (int off = 32; off > 0; off >>= 1) sred += __shfl_down(sred, off, 64);
  __shared__ float wsum[4];
  if (lane == 0) wsum[wv] = sred;
  __syncthreads();
  if (tid == 0) {
    atomicAdd(out, (wsum[0] + wsum[1] + wsum[2] + wsum[3]) *
                       (1.0f / (float)((size_t)Bd * Dd * Hd * Wd)));
  }
}

extern "C" void kernel_launch(void* const* d_in, const int* in_sizes, int n_in,
                              void* d_out, int out_size, void* d_ws, size_t ws_size,
                              hipStream_t stream) {
  const float* pred = (const float*)d_in[0];
  const float* targ = (const float*)d_in[1];
  float* out = (float*)d_out;
  (void)in_sizes; (void)n_in; (void)out_size; (void)d_ws; (void)ws_size;

  hipMemsetAsync(out, 0, sizeof(float), stream);
  dim3 grid(WGROUPS * HSUPER, NCHUNK, Bd);
  sobel_loss_kernel<<<grid, 256, 0, stream>>>(pred, targ, out);
}

// Round 10
// 42.895 us; speedup vs baseline: 3.6403x; 3.2536x over previous
//
#include <hip/hip_runtime.h>

namespace {
constexpr int Wd = 160, Hd = 192, Dd = 160, Bd = 2;
constexpr int HW = Hd * Wd;
constexpr int THREADS = 256;               // 4 waves
constexpr int ROWS_OUT = 6;                // output rows per block
constexpr int ROWS_LDS = 8;                // staged rows incl. h-halo
constexpr int RS = 164;                    // LDS row stride (floats)
constexpr int STRIPS = 40;                 // float4 strips per row
constexpr int CTHREADS = ROWS_OUT * STRIPS;   // 240 compute threads
constexpr int TASKS = 2 * ROWS_LDS * STRIPS;  // 640 staging tasks
constexpr int DCHUNK = 10;
constexpr int NCHUNK = Dd / DCHUNK;        // 16
constexpr int RGROUPS = Hd / ROWS_OUT;     // 32 -> grid 1024 = 4 blocks/CU
constexpr float EPS = 1e-8f;
}

__device__ __forceinline__ float dpp_up1(float v) {   // lane i <- lane i-1
  return __int_as_float(__builtin_amdgcn_update_dpp(
      0, __float_as_int(v), 0x138, 0xF, 0xF, true));  // wave_shr:1
}
__device__ __forceinline__ float dpp_dn1(float v) {   // lane i <- lane i+1
  return __int_as_float(__builtin_amdgcn_update_dpp(
      0, __float_as_int(v), 0x130, 0xF, 0xF, true));  // wave_shl:1
}

__global__ __launch_bounds__(THREADS) void sobel_loss_kernel(
    const float* __restrict__ pred, const float* __restrict__ targ,
    float* __restrict__ out) {
  // staged separable row partials: sw = [1,2,1]_w * x, dw = [-1,0,1]_w * x
  __shared__ float lsw[2][ROWS_LDS][RS];   // 10.5 KB
  __shared__ float ldw[2][ROWS_LDS][RS];   // 10.5 KB
  const int tid = threadIdx.x;
  const int lane = tid & 63;
  const int h0 = blockIdx.x * ROWS_OUT;
  const int d0 = blockIdx.y * DCHUNK;
  const size_t volOff = (size_t)blockIdx.z * Dd * HW;
  const float* pb = pred + volOff;
  const float* tb = targ + volOff;

  // ---- staging task decode (2.5 tasks/thread, loop-invariant) ----
  // task i -> tensor t_, row r8, strip s ; s is lane-contiguous => DPP halo
  const float* gs[3];
  float* psw[3];
  float* pdw[3];
  bool sok[3], rok[3], zL[3], zR[3], pL[3], pR[3];
#pragma unroll
  for (int u = 0; u < 3; ++u) {
    const int i = tid + 256 * u;
    const bool ok = (i < TASKS);
    const int ic = ok ? i : 0;
    const int t_ = ic / (ROWS_LDS * STRIPS);
    const int rem = ic - t_ * (ROWS_LDS * STRIPS);
    const int r8 = rem / STRIPS, s = rem - r8 * STRIPS;
    const int hh = h0 - 1 + r8;
    const bool rv = ok && ((unsigned)hh < (unsigned)Hd);
    sok[u] = ok;
    rok[u] = rv;
    zL[u] = (s == 0);                      // w zero-pad left
    zR[u] = (s == STRIPS - 1);             // w zero-pad right
    pL[u] = ok && (lane == 0) && (s != 0);            // wave-boundary patch
    pR[u] = ok && (lane == 63) && (s != STRIPS - 1);  // wave-boundary patch
    gs[u] = (t_ ? tb : pb) + (size_t)(rv ? hh : 0) * Wd + s * 4;
    psw[u] = &lsw[t_][r8][s * 4];
    pdw[u] = &ldw[t_][r8][s * 4];
  }

  float4 m[3];
  float hl[3], hr[3];
  auto GLOAD = [&](int d) {   // float4-only + <=2 exec-masked scalars per wave
    const bool dok = (unsigned)d < (unsigned)Dd;
    const size_t so = (size_t)d * HW;
#pragma unroll
    for (int u = 0; u < 3; ++u) {
      float4 v = make_float4(0.f, 0.f, 0.f, 0.f);
      float a = 0.f, b = 0.f;
      if (dok && rok[u]) {
        v = *reinterpret_cast<const float4*>(gs[u] + so);
        if (pL[u]) a = gs[u][so - 1];
        if (pR[u]) b = gs[u][so + 4];
      }
      m[u] = v; hl[u] = a; hr[u] = b;
    }
  };

  auto STAGE = [&]() {   // w-conv once per input row, write sw/dw to LDS
#pragma unroll
    for (int u = 0; u < 3; ++u) {
      float xl = dpp_up1(m[u].w);          // lane-1 holds x[4s-4..4s-1]
      float xr = dpp_dn1(m[u].x);          // lane+1 holds x[4s+4..4s+7]
      if (zL[u]) xl = 0.f;
      if (pL[u]) xl = hl[u];
      if (zR[u]) xr = 0.f;
      if (pR[u]) xr = hr[u];
      const float x0 = xl, x1 = m[u].x, x2 = m[u].y, x3 = m[u].z,
                  x4 = m[u].w, x5 = xr;
      float4 swv, dwv;
      swv.x = fmaf(2.f, x1, x0 + x2);  dwv.x = x2 - x0;
      swv.y = fmaf(2.f, x2, x1 + x3);  dwv.y = x3 - x1;
      swv.z = fmaf(2.f, x3, x2 + x4);  dwv.z = x4 - x2;
      swv.w = fmaf(2.f, x4, x3 + x5);  dwv.w = x5 - x3;
      if (sok[u]) {
        *reinterpret_cast<float4*>(psw[u]) = swv;
        *reinterpret_cast<float4*>(pdw[u]) = dwv;
      }
    }
  };

  // ---- compute decode: output row cr (0..5), strip cs (0..39) ----
  const int cr = tid / STRIPS;
  const int cs4 = (tid - cr * STRIPS) * 4;
  const bool is_c = (tid < CTHREADS);

  // rolling state [slot][tensor][j]
  float A[3][2][4], B[3][2][4], C[3][2][4];

  auto HCONV = [&](int slot) {   // h-conv only: 6 b128 reads + 20 VALU / tensor
#pragma unroll
    for (int t_ = 0; t_ < 2; ++t_) {
      const float4 sm = *reinterpret_cast<const float4*>(&lsw[t_][cr][cs4]);
      const float4 s0 = *reinterpret_cast<const float4*>(&lsw[t_][cr + 1][cs4]);
      const float4 sp = *reinterpret_cast<const float4*>(&lsw[t_][cr + 2][cs4]);
      const float4 dm = *reinterpret_cast<const float4*>(&ldw[t_][cr][cs4]);
      const float4 dd = *reinterpret_cast<const float4*>(&ldw[t_][cr + 1][cs4]);
      const float4 dp = *reinterpret_cast<const float4*>(&ldw[t_][cr + 2][cs4]);
      const float smv[4] = {sm.x, sm.y, sm.z, sm.w};
      const float s0v[4] = {s0.x, s0.y, s0.z, s0.w};
      const float spv[4] = {sp.x, sp.y, sp.z, sp.w};
      const float dmv[4] = {dm.x, dm.y, dm.z, dm.w};
      const float ddv[4] = {dd.x, dd.y, dd.z, dd.w};
      const float dpv[4] = {dp.x, dp.y, dp.z, dp.w};
#pragma unroll
      for (int j = 0; j < 4; ++j) {
        A[slot][t_][j] = fmaf(2.f, s0v[j], smv[j] + spv[j]);
        B[slot][t_][j] = fmaf(2.f, ddv[j], dmv[j] + dpv[j]);
        C[slot][t_][j] = spv[j] - smv[j];
      }
    }
  };

  float acc = 0.f;

  // ---- prologue: slices d0-1 (slot0) and d0 (slot1) ----
  GLOAD(d0 - 1);
  STAGE(); GLOAD(d0); __syncthreads();
  if (is_c) HCONV(0);
  __syncthreads();
  STAGE(); GLOAD(d0 + 1); __syncthreads();
  if (is_c) HCONV(1);
  __syncthreads();

  // ---- main loop, fully unrolled: output slice d0+k ----
#pragma unroll
  for (int k = 0; k < DCHUNK; ++k) {
    STAGE();                               // LDS <- slice d0+1+k (loaded last iter)
    if (k < DCHUNK - 1) GLOAD(d0 + 2 + k); // issue next; consumed next iter top
    __syncthreads();
    const int i0 = k % 3, i1 = (k + 1) % 3, i2 = (k + 2) % 3;
    if (is_c) {
      HCONV(i2);                           // state <- slice d0+1+k
#pragma unroll
      for (int j = 0; j < 4; ++j) {
        float gx = B[i0][0][j] + 2.f * B[i1][0][j] + B[i2][0][j];
        float gy = C[i0][0][j] + 2.f * C[i1][0][j] + C[i2][0][j];
        float gz = A[i2][0][j] - A[i0][0][j];
        const float pm = sqrtf(fmaf(gx, gx, fmaf(gy, gy, fmaf(gz, gz, EPS))));
        gx = B[i0][1][j] + 2.f * B[i1][1][j] + B[i2][1][j];
        gy = C[i0][1][j] + 2.f * C[i1][1][j] + C[i2][1][j];
        gz = A[i2][1][j] - A[i0][1][j];
        const float tm = sqrtf(fmaf(gx, gx, fmaf(gy, gy, fmaf(gz, gz, EPS))));
        acc += fabsf(pm - tm);
      }
    }
    __syncthreads();
  }

  // ---- reduction: wave shfl -> LDS -> one atomic per block ----
  float sred = acc;
#pragma unroll
  for (int off = 32; off > 0; off >>= 1) sred += __shfl_down(sred, off, 64);
  __shared__ float wsum[THREADS / 64];
  const int wid = tid >> 6;
  if (lane == 0) wsum[wid] = sred;
  __syncthreads();
  if (tid == 0) {
    float t = 0.f;
#pragma unroll
    for (int i = 0; i < THREADS / 64; ++i) t += wsum[i];
    atomicAdd(out, t * (1.0f / (float)((size_t)Bd * Dd * Hd * Wd)));
  }
}

extern "C" void kernel_launch(void* const* d_in, const int* in_sizes, int n_in,
                              void* d_out, int out_size, void* d_ws, size_t ws_size,
                              hipStream_t stream) {
  const float* pred = (const float*)d_in[0];
  const float* targ = (const float*)d_in[1];
  float* out = (float*)d_out;
  (void)in_sizes; (void)n_in; (void)out_size; (void)d_ws; (void)ws_size;

  hipMemsetAsync(out, 0, sizeof(float), stream);
  dim3 grid(RGROUPS, NCHUNK, Bd);
  sobel_loss_kernel<<<grid, THREADS, 0, stream>>>(pred, targ, out);
}